// Round 3
// baseline (1207.504 us; speedup 1.0000x reference)
//
#include <hip/hip_runtime.h>

typedef unsigned short u16;
typedef short bf16x8 __attribute__((ext_vector_type(8)));
typedef float f32x4 __attribute__((ext_vector_type(4)));

__device__ __forceinline__ u16 f2bf(float f) {
    unsigned u = __float_as_uint(f);
    u = (u + 0x7fffu + ((u >> 16) & 1u)) >> 16;
    return (u16)u;
}
__device__ __forceinline__ float bf2f(u16 h) {
    return __uint_as_float(((unsigned)h) << 16);
}
// cheap round-to-nearest pack (a -> low16, b -> high16)
__device__ __forceinline__ unsigned pk2c(float a, float b) {
    return ((__float_as_uint(a) + 0x8000u) >> 16) |
           ((__float_as_uint(b) + 0x8000u) & 0xffff0000u);
}
__device__ __forceinline__ void async16(void* lds, const void* g) {
    __builtin_amdgcn_global_load_lds(
        (const __attribute__((address_space(1))) void*)g,
        (__attribute__((address_space(3))) void*)lds, 16, 0, 0);
}

union U4BF8 { uint4 u; bf16x8 v; };

// ---------------------------------------------------------------------------
// prep_weights: WpT bf16 [256][2048] (=Wp^T); WT bf16 [1536][256]
// (rows: q 0..511 | k 512..1023 | v 1024..1535; col = D index). Writes coalesced.
// ---------------------------------------------------------------------------
__global__ __launch_bounds__(256) void prep_weights(
    const float* __restrict__ Wp, const float* __restrict__ Wq,
    const float* __restrict__ Wk, const float* __restrict__ Wv,
    u16* __restrict__ WpT, u16* __restrict__ WT)
{
    int id = blockIdx.x * 256 + threadIdx.x;   // 0 .. 917503
    if (id < 524288) {
        int n = id >> 11, k = id & 2047;
        WpT[(size_t)n * 2048 + k] = f2bf(Wp[(size_t)k * 256 + n]);
    } else {
        int id2 = id - 524288;
        int k = id2 & 255;
        int o = (id2 >> 8) & 511;
        int mat = id2 >> 17;                                 // 0..2
        const float* W = (mat == 0) ? Wq : (mat == 1) ? Wk : Wv;
        WT[(size_t)(mat * 512 + o) * 256 + k] = f2bf(W[(size_t)k * 512 + o]);
    }
}

// ---------------------------------------------------------------------------
// prep_small: blocks 0..7: Wsr[256][6] = Ws @ Wr (32 d-rows per block).
// block 8: mask M[dst][src] = ln(mult) / -1e30, and c0[6] = (bs+bv)@Wr + br.
// ---------------------------------------------------------------------------
__global__ __launch_bounds__(256) void prep_small(
    const int* __restrict__ ei, const float* __restrict__ Wsf,
    const float* __restrict__ Wr, const float* __restrict__ bsf,
    const float* __restrict__ bvf, const float* __restrict__ brf,
    float* __restrict__ Mm, float* __restrict__ Wsr, float* __restrict__ c0)
{
    int t = threadIdx.x, bx = blockIdx.x;
    if (bx < 8) {
        int d = bx * 32 + (t >> 3);
        int os = t & 7;
        float a[6] = {0.f, 0.f, 0.f, 0.f, 0.f, 0.f};
        for (int i = 0; i < 64; ++i) {
            int o = os * 64 + i;
            float w = Wsf[(size_t)d * 512 + o];
#pragma unroll
            for (int j = 0; j < 6; ++j) a[j] += w * Wr[o * 6 + j];
        }
#pragma unroll
        for (int j = 0; j < 6; ++j) {
            a[j] += __shfl_xor(a[j], 1);
            a[j] += __shfl_xor(a[j], 2);
            a[j] += __shfl_xor(a[j], 4);
        }
        if (os == 0) {
#pragma unroll
            for (int j = 0; j < 6; ++j) Wsr[d * 6 + j] = a[j];
        }
    } else {
        __shared__ int cnt[4096];
        __shared__ float c6[6];
        for (int i = t; i < 4096; i += 256) cnt[i] = 0;
        if (t < 6) c6[t] = 0.f;
        __syncthreads();
        for (int e = t; e < 1024; e += 256) {
            int s = ei[e];
            int d = ei[1024 + e];
            atomicAdd(&cnt[d * 64 + s], 1);
        }
        __syncthreads();
        for (int i = t; i < 4096; i += 256) {
            int c = cnt[i];
            Mm[i] = (c > 0) ? logf((float)c) : -1e30f;
        }
        // c0
        float a[6] = {0.f, 0.f, 0.f, 0.f, 0.f, 0.f};
        for (int o = t; o < 512; o += 256) {
            float bb = bsf[o] + bvf[o];
#pragma unroll
            for (int j = 0; j < 6; ++j) a[j] += bb * Wr[o * 6 + j];
        }
#pragma unroll
        for (int j = 0; j < 6; ++j) {
            float v = a[j];
            for (int off = 32; off; off >>= 1) v += __shfl_down(v, off);
            if ((t & 63) == 0) atomicAdd(&c6[j], v);
        }
        __syncthreads();
        if (t < 6) c0[t] = c6[t] + brf[t];
    }
}

// ---------------------------------------------------------------------------
// gemm1 (LDS-free, barrier-free): Xp_bf16[65536][256] = bf16(X) @ bf16(Wp) + bp
// Each wave owns a 64x64 tile; A frags stream from X (fp32->bf16 in regs),
// B frags stream from L2-resident WpT. Register ping-pong double buffer.
// grid = (2, 512): both N-halves of the same M-rows adjacent for L2 reuse.
// ---------------------------------------------------------------------------
__global__ __launch_bounds__(256, 2) void gemm1(const float* __restrict__ X,
                                                const u16* __restrict__ WpT,
                                                const float* __restrict__ bp,
                                                u16* __restrict__ Xp)
{
    const int t = threadIdx.x;
    const int lane = t & 63, wave = t >> 6;
    const int n0 = blockIdx.x * 128;     // gridDim.x = 2
    const int m0 = blockIdx.y * 128;     // gridDim.y = 512
    const int wm = (wave >> 1) * 64, wn = (wave & 1) * 64;
    const int lr = lane & 15, q8 = lane >> 4;

    const float* Ab = X + (size_t)(m0 + wm + lr) * 2048 + q8 * 8;
    const u16*   Bb = WpT + (size_t)(n0 + wn + lr) * 2048 + q8 * 8;

    const f32x4 z4 = {0.f, 0.f, 0.f, 0.f};
    f32x4 acc[4][4];
#pragma unroll
    for (int i = 0; i < 4; ++i)
#pragma unroll
        for (int j = 0; j < 4; ++j) acc[i][j] = z4;

    float4 a0[4][2], a1[4][2];
    bf16x8 b0[4], b1[4];

#pragma unroll
    for (int i = 0; i < 4; ++i) {
        a0[i][0] = *(const float4*)(Ab + i * 32768);
        a0[i][1] = *(const float4*)(Ab + i * 32768 + 4);
    }
#pragma unroll
    for (int j = 0; j < 4; ++j)
        b0[j] = *(const bf16x8*)(Bb + j * 32768);

#define G1_BODY(AB, BB)                                                     \
    {                                                                       \
        bf16x8 af[4];                                                       \
        _Pragma("unroll")                                                   \
        for (int i = 0; i < 4; ++i) {                                       \
            U4BF8 u;                                                        \
            u.u.x = pk2c(AB[i][0].x, AB[i][0].y);                           \
            u.u.y = pk2c(AB[i][0].z, AB[i][0].w);                           \
            u.u.z = pk2c(AB[i][1].x, AB[i][1].y);                           \
            u.u.w = pk2c(AB[i][1].z, AB[i][1].w);                           \
            af[i] = u.v;                                                    \
        }                                                                   \
        _Pragma("unroll")                                                   \
        for (int i = 0; i < 4; ++i)                                         \
            _Pragma("unroll")                                               \
            for (int j = 0; j < 4; ++j)                                     \
                acc[i][j] = __builtin_amdgcn_mfma_f32_16x16x32_bf16(        \
                    af[i], BB[j], acc[i][j], 0, 0, 0);                      \
    }

    for (int kk = 0; kk < 64; kk += 2) {
        {   // prefetch kk+1 -> buf1 (kk+1 <= 63 always)
            const int k1 = (kk + 1) * 32;
#pragma unroll
            for (int i = 0; i < 4; ++i) {
                a1[i][0] = *(const float4*)(Ab + i * 32768 + k1);
                a1[i][1] = *(const float4*)(Ab + i * 32768 + k1 + 4);
            }
#pragma unroll
            for (int j = 0; j < 4; ++j)
                b1[j] = *(const bf16x8*)(Bb + j * 32768 + k1);
        }
        G1_BODY(a0, b0)
        if (kk < 62) {   // prefetch kk+2 -> buf0
            const int k2 = (kk + 2) * 32;
#pragma unroll
            for (int i = 0; i < 4; ++i) {
                a0[i][0] = *(const float4*)(Ab + i * 32768 + k2);
                a0[i][1] = *(const float4*)(Ab + i * 32768 + k2 + 4);
            }
#pragma unroll
            for (int j = 0; j < 4; ++j)
                b0[j] = *(const bf16x8*)(Bb + j * 32768 + k2);
        }
        G1_BODY(a1, b1)
    }
#undef G1_BODY

#pragma unroll
    for (int j = 0; j < 4; ++j) {
        const int col = n0 + wn + j * 16 + lr;
        const float bias = bp[col];
#pragma unroll
        for (int i = 0; i < 4; ++i)
#pragma unroll
            for (int r = 0; r < 4; ++r) {
                int row = m0 + wm + i * 16 + q8 * 4 + r;
                Xp[(size_t)row * 256 + col] = f2bf(acc[i][j][r] + bias);
            }
    }
}

// ---------------------------------------------------------------------------
// skip_out: out[b][:] = xbar[b] @ Wsr + c0   (pre-writes output; attn adds)
// ---------------------------------------------------------------------------
__global__ __launch_bounds__(256) void skip_out(const u16* __restrict__ Xp,
                                                const float* __restrict__ Wsr,
                                                const float* __restrict__ c0,
                                                float* __restrict__ out)
{
    __shared__ float acc6[6];
    int t = threadIdx.x, b = blockIdx.x;
    if (t < 6) acc6[t] = 0.f;
    __syncthreads();
    const u16* xg = Xp + (size_t)b * 16384;
    float s = 0.f;
#pragma unroll 8
    for (int n = 0; n < 64; ++n) s += bf2f(xg[n * 256 + t]);
    float xv = s * (1.0f / 64.0f);
#pragma unroll
    for (int j = 0; j < 6; ++j) {
        float v = xv * Wsr[t * 6 + j];
        for (int off = 32; off; off >>= 1) v += __shfl_down(v, off);
        if ((t & 63) == 0) atomicAdd(&acc6[j], v);
    }
    __syncthreads();
    if (t < 6) out[b * 6 + t] = acc6[t] + c0[t];
}

// ---------------------------------------------------------------------------
// attn: one block per (b,h). Stage Xp[b] -> LDS; QKV via MFMA (B from L2);
// S = qk^T/8 + mask (MFMA); in-register softmax; colsum(Pn)/64 -> w;
// y = w @ V; out[b] += y @ Wr_h  (6 atomics).
// ---------------------------------------------------------------------------
__global__ __launch_bounds__(256, 2) void attn(
    const u16* __restrict__ Xp, const u16* __restrict__ WT,
    const float* __restrict__ Mm, const float* __restrict__ bq,
    const float* __restrict__ bk, const float* __restrict__ Wr,
    float* __restrict__ out)
{
    __shared__ alignas(16) u16 Xs[64 * 256];
    __shared__ alignas(16) u16 Qs[64 * 72];
    __shared__ alignas(16) u16 Ks[64 * 72];
    __shared__ alignas(16) u16 Vs[64 * 72];
    __shared__ float w_l[64];
    __shared__ float y_l[64];

    const int t = threadIdx.x;
    const int lane = t & 63, wave = t >> 6;
    const int lr = lane & 15, q8 = lane >> 4;
    const int bh = blockIdx.x, b = bh >> 3, h = bh & 7;
    const f32x4 z4 = {0.f, 0.f, 0.f, 0.f};

    if (t < 64) { w_l[t] = 0.f; y_l[t] = 0.f; }

    {   // stage Xp[b] -> Xs, XOR-swizzled 16B chunks
        const u16* xg = Xp + (size_t)b * 16384;
#pragma unroll
        for (int it = 0; it < 8; ++it) {
            int c = it * 256 + t;
            int row = c >> 5, s = c & 31;
            int g = (s & 24) | ((s & 7) ^ (row & 7));
            async16(&Xs[(it * 256 + wave * 64) * 8], xg + (size_t)row * 256 + g * 8);
        }
    }
    __syncthreads();

    // --- QKV GEMM: 12 col-tiles of 16 (q0-3,k4-7,v8-11); wave owns 3
    f32x4 acc[3][4];
#pragma unroll
    for (int jt = 0; jt < 3; ++jt)
#pragma unroll
        for (int i = 0; i < 4; ++i) acc[jt][i] = z4;
    const int jj0 = wave * 3;
#pragma unroll 2
    for (int kk = 0; kk < 8; ++kk) {
        bf16x8 af[4];
#pragma unroll
        for (int i = 0; i < 4; ++i) {
            int m = i * 16 + lr;
            int g = kk * 4 + q8;
            int s = (g & 24) | ((g & 7) ^ (m & 7));
            af[i] = *(const bf16x8*)&Xs[m * 256 + s * 8];
        }
#pragma unroll
        for (int jt = 0; jt < 3; ++jt) {
            int jj = jj0 + jt, sec = jj >> 2;
            int r = sec * 512 + h * 64 + (jj & 3) * 16 + lr;
            bf16x8 bfv = *(const bf16x8*)(WT + (size_t)r * 256 + kk * 32 + q8 * 8);
#pragma unroll
            for (int i = 0; i < 4; ++i)
                acc[jt][i] = __builtin_amdgcn_mfma_f32_16x16x32_bf16(
                    af[i], bfv, acc[jt][i], 0, 0, 0);
        }
    }
    // epilogue -> LDS (pad 72); q scaled 1/8 w/ bias, k w/ bias, v raw
#pragma unroll
    for (int jt = 0; jt < 3; ++jt) {
        int jj = jj0 + jt, sec = jj >> 2;
        int colh = (jj & 3) * 16 + lr;
        float bias = (sec == 0) ? bq[h * 64 + colh]
                   : (sec == 1) ? bk[h * 64 + colh] : 0.f;
#pragma unroll
        for (int i = 0; i < 4; ++i)
#pragma unroll
            for (int r2 = 0; r2 < 4; ++r2) {
                int row = i * 16 + q8 * 4 + r2;
                float v = acc[jt][i][r2] + bias;
                if (sec == 0)      Qs[row * 72 + colh] = f2bf(v * 0.125f);
                else if (sec == 1) Ks[row * 72 + colh] = f2bf(v);
                else               Vs[row * 72 + colh] = f2bf(v);
            }
    }
    __syncthreads();

    // --- S-MFMA: wave owns dst rows wave*16..+15
    f32x4 sacc[4];
#pragma unroll
    for (int j = 0; j < 4; ++j) sacc[j] = z4;
#pragma unroll
    for (int k2 = 0; k2 < 2; ++k2) {
        bf16x8 aq = *(const bf16x8*)&Qs[(wave * 16 + lr) * 72 + k2 * 32 + q8 * 8];
#pragma unroll
        for (int j = 0; j < 4; ++j) {
            bf16x8 bk8 = *(const bf16x8*)&Ks[(j * 16 + lr) * 72 + k2 * 32 + q8 * 8];
            sacc[j] = __builtin_amdgcn_mfma_f32_16x16x32_bf16(aq, bk8, sacc[j], 0, 0, 0);
        }
    }
    // --- mask + in-register softmax (rows in C layout)
    const int dst0 = wave * 16 + q8 * 4;
    float p[4][4];
#pragma unroll
    for (int r2 = 0; r2 < 4; ++r2) {
        float m = -1e38f;
#pragma unroll
        for (int j = 0; j < 4; ++j) {
            sacc[j][r2] += Mm[(dst0 + r2) * 64 + j * 16 + lr];
            m = fmaxf(m, sacc[j][r2]);
        }
        m = fmaxf(m, __shfl_xor(m, 1));
        m = fmaxf(m, __shfl_xor(m, 2));
        m = fmaxf(m, __shfl_xor(m, 4));
        m = fmaxf(m, __shfl_xor(m, 8));
        bool dead = (m < -1e29f);
        float rs = 0.f;
#pragma unroll
        for (int j = 0; j < 4; ++j) {
            float pv = dead ? 0.f : __expf(sacc[j][r2] - m);
            p[j][r2] = pv;
            rs += pv;
        }
        rs += __shfl_xor(rs, 1);
        rs += __shfl_xor(rs, 2);
        rs += __shfl_xor(rs, 4);
        rs += __shfl_xor(rs, 8);
        float sc = 1.0f / (rs + 1e-16f) * (1.0f / 64.0f);
#pragma unroll
        for (int j = 0; j < 4; ++j) p[j][r2] *= sc;
    }
    // --- column sums -> w_l
#pragma unroll
    for (int j = 0; j < 4; ++j) {
        float cw = p[j][0] + p[j][1] + p[j][2] + p[j][3];
        cw += __shfl_xor(cw, 16);
        cw += __shfl_xor(cw, 32);
        if (lane < 16) atomicAdd(&w_l[j * 16 + lr], cw);
    }
    __syncthreads();
    // --- y[c] = sum_src w[src] * V[src][c]
    {
        int c = t & 63, sg = t >> 6;
        float part = 0.f;
#pragma unroll
        for (int i = 0; i < 16; ++i) {
            int src = sg * 16 + i;
            part += w_l[src] * bf2f(Vs[src * 72 + c]);
        }
        atomicAdd(&y_l[c], part);
    }
    __syncthreads();
    // --- out[b] += y @ Wr_h
    if (t < 64) {
        float yv = y_l[t];
#pragma unroll
        for (int j = 0; j < 6; ++j) {
            float v = yv * Wr[(h * 64 + t) * 6 + j];
            for (int off = 32; off; off >>= 1) v += __shfl_down(v, off);
            if (t == 0) atomicAdd(&out[b * 6 + j], v);
        }
    }
}

// ---------------------------------------------------------------------------
extern "C" void kernel_launch(void* const* d_in, const int* in_sizes, int n_in,
                              void* d_out, int out_size, void* d_ws, size_t ws_size,
                              hipStream_t stream)
{
    (void)in_sizes; (void)n_in; (void)out_size; (void)ws_size;
    const float* X  = (const float*)d_in[0];
    const int*   ei = (const int*)d_in[1];
    const float* Wp = (const float*)d_in[2];
    const float* bp = (const float*)d_in[3];
    const float* Wq = (const float*)d_in[4];
    const float* bq = (const float*)d_in[5];
    const float* Wk = (const float*)d_in[6];
    const float* bk = (const float*)d_in[7];
    const float* Wv = (const float*)d_in[8];
    const float* bv = (const float*)d_in[9];
    const float* Wsk = (const float*)d_in[10];
    const float* bs = (const float*)d_in[11];
    const float* Wr = (const float*)d_in[12];
    const float* br = (const float*)d_in[13];
    float* out = (float*)d_out;

    char* ws = (char*)d_ws;
    u16*   WpT = (u16*)(ws);                                  // 1 MiB
    u16*   WT  = (u16*)(ws + (1u << 20));                     // 768 KiB
    float* Mm  = (float*)(ws + 0x1C0000u);                    // 16 KiB
    float* Wsr = (float*)(ws + 0x1C4000u);                    // 6 KiB
    float* c0  = (float*)(ws + 0x1C8000u);                    // 24 B
    u16*   Xp  = (u16*)(ws + (2u << 20));                     // 32 MiB

    hipLaunchKernelGGL(prep_weights, dim3(3584), dim3(256), 0, stream,
                       Wp, Wq, Wk, Wv, WpT, WT);
    hipLaunchKernelGGL(prep_small, dim3(9), dim3(256), 0, stream,
                       ei, Wsk, Wr, bs, bv, br, Mm, Wsr, c0);
    hipLaunchKernelGGL(gemm1, dim3(2, 512), dim3(256), 0, stream, X, WpT, bp, Xp);
    hipLaunchKernelGGL(skip_out, dim3(1024), dim3(256), 0, stream, Xp, Wsr, c0, out);
    hipLaunchKernelGGL(attn, dim3(8192), dim3(256), 0, stream,
                       Xp, WT, Mm, bq, bk, Wr, out);
}

// Round 4
// 1059.176 us; speedup vs baseline: 1.1400x; 1.1400x over previous
//
#include <hip/hip_runtime.h>

typedef unsigned short u16;
typedef short bf16x8 __attribute__((ext_vector_type(8)));
typedef float f32x4 __attribute__((ext_vector_type(4)));

__device__ __forceinline__ u16 f2bf(float f) {
    unsigned u = __float_as_uint(f);
    u = (u + 0x7fffu + ((u >> 16) & 1u)) >> 16;
    return (u16)u;
}
__device__ __forceinline__ float bf2f(u16 h) {
    return __uint_as_float(((unsigned)h) << 16);
}
// cheap round-to-nearest pack (a -> low16, b -> high16)
__device__ __forceinline__ unsigned pk2c(float a, float b) {
    return ((__float_as_uint(a) + 0x8000u) >> 16) |
           ((__float_as_uint(b) + 0x8000u) & 0xffff0000u);
}
__device__ __forceinline__ void async16(void* lds, const void* g) {
    __builtin_amdgcn_global_load_lds(
        (const __attribute__((address_space(1))) void*)g,
        (__attribute__((address_space(3))) void*)lds, 16, 0, 0);
}

union U4BF8 { uint4 u; bf16x8 v; };

// ---------------------------------------------------------------------------
// transpose_cvt: dst[c][r] = bf16(src[r][c]); 64x64 LDS tiles, both sides
// coalesced. grid = (C/64, R/64).
// ---------------------------------------------------------------------------
__global__ __launch_bounds__(256) void transpose_cvt(
    const float* __restrict__ src, u16* __restrict__ dst, int R, int C)
{
    __shared__ float tile[64][65];
    const int t = threadIdx.x;
    const int lane = t & 63, wave = t >> 6;
    const int c0 = blockIdx.x * 64, r0 = blockIdx.y * 64;
#pragma unroll
    for (int rr = 0; rr < 16; ++rr) {
        int rl = rr * 4 + wave;
        tile[rl][lane] = src[(size_t)(r0 + rl) * C + c0 + lane];
    }
    __syncthreads();
#pragma unroll
    for (int rr = 0; rr < 16; ++rr) {
        int cl = rr * 4 + wave;
        dst[(size_t)(c0 + cl) * R + r0 + lane] = f2bf(tile[lane][cl]);
    }
}

// ---------------------------------------------------------------------------
// prep_small: blocks 0..7: Wsr[256][6] = Ws @ Wr (32 d-rows per block).
// block 8: mask M[dst][src] = ln(mult) / -1e30, and c0[6] = (bs+bv)@Wr + br.
// ---------------------------------------------------------------------------
__global__ __launch_bounds__(256) void prep_small(
    const int* __restrict__ ei, const float* __restrict__ Wsf,
    const float* __restrict__ Wr, const float* __restrict__ bsf,
    const float* __restrict__ bvf, const float* __restrict__ brf,
    float* __restrict__ Mm, float* __restrict__ Wsr, float* __restrict__ c0)
{
    int t = threadIdx.x, bx = blockIdx.x;
    if (bx < 8) {
        int d = bx * 32 + (t >> 3);
        int os = t & 7;
        float a[6] = {0.f, 0.f, 0.f, 0.f, 0.f, 0.f};
        for (int i = 0; i < 64; ++i) {
            int o = os * 64 + i;
            float w = Wsf[(size_t)d * 512 + o];
#pragma unroll
            for (int j = 0; j < 6; ++j) a[j] += w * Wr[o * 6 + j];
        }
#pragma unroll
        for (int j = 0; j < 6; ++j) {
            a[j] += __shfl_xor(a[j], 1);
            a[j] += __shfl_xor(a[j], 2);
            a[j] += __shfl_xor(a[j], 4);
        }
        if (os == 0) {
#pragma unroll
            for (int j = 0; j < 6; ++j) Wsr[d * 6 + j] = a[j];
        }
    } else {
        __shared__ int cnt[4096];
        __shared__ float c6[6];
        for (int i = t; i < 4096; i += 256) cnt[i] = 0;
        if (t < 6) c6[t] = 0.f;
        __syncthreads();
        for (int e = t; e < 1024; e += 256) {
            int s = ei[e];
            int d = ei[1024 + e];
            atomicAdd(&cnt[d * 64 + s], 1);
        }
        __syncthreads();
        for (int i = t; i < 4096; i += 256) {
            int c = cnt[i];
            Mm[i] = (c > 0) ? logf((float)c) : -1e30f;
        }
        // c0
        float a[6] = {0.f, 0.f, 0.f, 0.f, 0.f, 0.f};
        for (int o = t; o < 512; o += 256) {
            float bb = bsf[o] + bvf[o];
#pragma unroll
            for (int j = 0; j < 6; ++j) a[j] += bb * Wr[o * 6 + j];
        }
#pragma unroll
        for (int j = 0; j < 6; ++j) {
            float v = a[j];
            for (int off = 32; off; off >>= 1) v += __shfl_down(v, off);
            if ((t & 63) == 0) atomicAdd(&c6[j], v);
        }
        __syncthreads();
        if (t < 6) c0[t] = c6[t] + brf[t];
    }
}

// ---------------------------------------------------------------------------
// gemm1: Xp_bf16[65536][256] = bf16(X[65536][2048]) @ bf16(Wp) + bp
// Tile 64(M) x 256(N=all) x 32(K). ALL staging via global_load_lds (async
// DMA, no VGPR round trip, no mid-loop vmem waits). A stored fp32 with
// 144-B rows (9 chunks; chunk 8 = dup of chunk 0 -> 2-way-only bank alias).
// B from WpT with 80-B rows (5 chunks, chunk 4 dup). 4 waves, each owns
// 16 rows x 256 cols (acc = 16 x f32x4 = 64 VGPR). Small LDS (29.7 KB) ->
// 4-5 resident blocks/CU stagger the per-iteration vmcnt drain.
// ---------------------------------------------------------------------------
__global__ __launch_bounds__(256, 4) void gemm1(const float* __restrict__ X,
                                                const u16* __restrict__ WpT,
                                                const float* __restrict__ bp,
                                                u16* __restrict__ Xp)
{
    __shared__ alignas(16) float As[64 * 36];   // 9216 B
    __shared__ alignas(16) u16   Bs[256 * 40];  // 20480 B
    const int t = threadIdx.x;
    const int lane = t & 63, wave = t >> 6;
    const int lr = lane & 15, q8 = lane >> 4;
    const int m0 = blockIdx.x * 64;

    // --- per-lane DMA source pointers (row/part via exact magic division) ---
    // A: 576 chunks of 16 B, c -> row=c/9, part=c%9 (part 8 duplicates part 0)
    const int ca0 = t, ca1 = 256 + t, ca2 = 512 + lane;
    const int ra0 = (ca0 * 7282) >> 16, pa0 = ca0 - ra0 * 9;
    const int ra1 = (ca1 * 7282) >> 16, pa1 = ca1 - ra1 * 9;
    const int ra2 = (ca2 * 7282) >> 16, pa2 = ca2 - ra2 * 9;
    const float* pA0 = X + (size_t)(m0 + ra0) * 2048 + (pa0 == 8 ? 0 : pa0 * 4);
    const float* pA1 = X + (size_t)(m0 + ra1) * 2048 + (pa1 == 8 ? 0 : pa1 * 4);
    const float* pA2 = X + (size_t)(m0 + ra2) * 2048 + (pa2 == 8 ? 0 : pa2 * 4);
    // B: 1280 chunks of 16 B, c -> n=c/5, part=c%5 (part 4 duplicates part 0)
    const u16* pB[5];
#pragma unroll
    for (int i = 0; i < 5; ++i) {
        int c = i * 256 + t;
        int n = (c * 13108) >> 16;
        int prt = c - n * 5;
        pB[i] = WpT + (size_t)n * 2048 + (prt == 4 ? 0 : prt * 8);
    }

    const f32x4 z4 = {0.f, 0.f, 0.f, 0.f};
    f32x4 acc[16];
#pragma unroll
    for (int j = 0; j < 16; ++j) acc[j] = z4;

    const int arow = (wave * 16 + lr) * 36 + q8 * 8;

    for (int kk = 0; kk < 64; ++kk) {
        const int k0 = kk * 32;
        // ---- async DMA staging (only waits are at the barrier) ----
        async16(&As[(size_t)ca0 * 4], pA0 + k0);
        async16(&As[(size_t)ca1 * 4], pA1 + k0);
        if (wave == 0) async16(&As[(size_t)ca2 * 4], pA2 + k0);
#pragma unroll
        for (int i = 0; i < 5; ++i)
            async16(&Bs[(size_t)(i * 256 + t) * 8], pB[i] + k0);
        __syncthreads();
        // ---- compute: 1 A-frag (fp32->bf16 pack), 16 B-frags, 16 MFMA ----
        const float4 af0 = *(const float4*)&As[arow];
        const float4 af1 = *(const float4*)&As[arow + 4];
        U4BF8 ua;
        ua.u.x = pk2c(af0.x, af0.y);
        ua.u.y = pk2c(af0.z, af0.w);
        ua.u.z = pk2c(af1.x, af1.y);
        ua.u.w = pk2c(af1.z, af1.w);
        const bf16x8 a = ua.v;
#pragma unroll
        for (int j = 0; j < 16; ++j) {
            const bf16x8 b = *(const bf16x8*)&Bs[(j * 16 + lr) * 40 + q8 * 8];
            acc[j] = __builtin_amdgcn_mfma_f32_16x16x32_bf16(a, b, acc[j], 0, 0, 0);
        }
        __syncthreads();
    }

#pragma unroll
    for (int j = 0; j < 16; ++j) {
        const int col = j * 16 + lr;
        const float bias = bp[col];
#pragma unroll
        for (int r = 0; r < 4; ++r) {
            int row = m0 + wave * 16 + q8 * 4 + r;
            Xp[(size_t)row * 256 + col] = f2bf(acc[j][r] + bias);
        }
    }
}

// ---------------------------------------------------------------------------
// skip_out: out[b][:] = xbar[b] @ Wsr + c0   (pre-writes output; attn adds)
// ---------------------------------------------------------------------------
__global__ __launch_bounds__(256) void skip_out(const u16* __restrict__ Xp,
                                                const float* __restrict__ Wsr,
                                                const float* __restrict__ c0,
                                                float* __restrict__ out)
{
    __shared__ float acc6[6];
    int t = threadIdx.x, b = blockIdx.x;
    if (t < 6) acc6[t] = 0.f;
    __syncthreads();
    const u16* xg = Xp + (size_t)b * 16384;
    float s = 0.f;
#pragma unroll 8
    for (int n = 0; n < 64; ++n) s += bf2f(xg[n * 256 + t]);
    float xv = s * (1.0f / 64.0f);
#pragma unroll
    for (int j = 0; j < 6; ++j) {
        float v = xv * Wsr[t * 6 + j];
        for (int off = 32; off; off >>= 1) v += __shfl_down(v, off);
        if ((t & 63) == 0) atomicAdd(&acc6[j], v);
    }
    __syncthreads();
    if (t < 6) out[b * 6 + t] = acc6[t] + c0[t];
}

// ---------------------------------------------------------------------------
// attn: one block per (b,h). Stage Xp[b] -> LDS; QKV via MFMA (B from L2);
// S = qk^T/8 + mask (MFMA); in-register softmax; colsum(Pn)/64 -> w;
// y = w @ V; out[b] += y @ Wr_h  (6 atomics).
// ---------------------------------------------------------------------------
__global__ __launch_bounds__(256, 2) void attn(
    const u16* __restrict__ Xp, const u16* __restrict__ WT,
    const float* __restrict__ Mm, const float* __restrict__ bq,
    const float* __restrict__ bk, const float* __restrict__ Wr,
    float* __restrict__ out)
{
    __shared__ alignas(16) u16 Xs[64 * 256];
    __shared__ alignas(16) u16 Qs[64 * 72];
    __shared__ alignas(16) u16 Ks[64 * 72];
    __shared__ alignas(16) u16 Vs[64 * 72];
    __shared__ float w_l[64];
    __shared__ float y_l[64];

    const int t = threadIdx.x;
    const int lane = t & 63, wave = t >> 6;
    const int lr = lane & 15, q8 = lane >> 4;
    const int bh = blockIdx.x, b = bh >> 3, h = bh & 7;
    const f32x4 z4 = {0.f, 0.f, 0.f, 0.f};

    if (t < 64) { w_l[t] = 0.f; y_l[t] = 0.f; }

    {   // stage Xp[b] -> Xs, XOR-swizzled 16B chunks
        const u16* xg = Xp + (size_t)b * 16384;
#pragma unroll
        for (int it = 0; it < 8; ++it) {
            int c = it * 256 + t;
            int row = c >> 5, s = c & 31;
            int g = (s & 24) | ((s & 7) ^ (row & 7));
            async16(&Xs[(it * 256 + wave * 64) * 8], xg + (size_t)row * 256 + g * 8);
        }
    }
    __syncthreads();

    // --- QKV GEMM: 12 col-tiles of 16 (q0-3,k4-7,v8-11); wave owns 3
    f32x4 acc[3][4];
#pragma unroll
    for (int jt = 0; jt < 3; ++jt)
#pragma unroll
        for (int i = 0; i < 4; ++i) acc[jt][i] = z4;
    const int jj0 = wave * 3;
#pragma unroll 2
    for (int kk = 0; kk < 8; ++kk) {
        bf16x8 af[4];
#pragma unroll
        for (int i = 0; i < 4; ++i) {
            int m = i * 16 + lr;
            int g = kk * 4 + q8;
            int s = (g & 24) | ((g & 7) ^ (m & 7));
            af[i] = *(const bf16x8*)&Xs[m * 256 + s * 8];
        }
#pragma unroll
        for (int jt = 0; jt < 3; ++jt) {
            int jj = jj0 + jt, sec = jj >> 2;
            int r = sec * 512 + h * 64 + (jj & 3) * 16 + lr;
            bf16x8 bfv = *(const bf16x8*)(WT + (size_t)r * 256 + kk * 32 + q8 * 8);
#pragma unroll
            for (int i = 0; i < 4; ++i)
                acc[jt][i] = __builtin_amdgcn_mfma_f32_16x16x32_bf16(
                    af[i], bfv, acc[jt][i], 0, 0, 0);
        }
    }
    // epilogue -> LDS (pad 72); q scaled 1/8 w/ bias, k w/ bias, v raw
#pragma unroll
    for (int jt = 0; jt < 3; ++jt) {
        int jj = jj0 + jt, sec = jj >> 2;
        int colh = (jj & 3) * 16 + lr;
        float bias = (sec == 0) ? bq[h * 64 + colh]
                   : (sec == 1) ? bk[h * 64 + colh] : 0.f;
#pragma unroll
        for (int i = 0; i < 4; ++i)
#pragma unroll
            for (int r2 = 0; r2 < 4; ++r2) {
                int row = i * 16 + q8 * 4 + r2;
                float v = acc[jt][i][r2] + bias;
                if (sec == 0)      Qs[row * 72 + colh] = f2bf(v * 0.125f);
                else if (sec == 1) Ks[row * 72 + colh] = f2bf(v);
                else               Vs[row * 72 + colh] = f2bf(v);
            }
    }
    __syncthreads();

    // --- S-MFMA: wave owns dst rows wave*16..+15
    f32x4 sacc[4];
#pragma unroll
    for (int j = 0; j < 4; ++j) sacc[j] = z4;
#pragma unroll
    for (int k2 = 0; k2 < 2; ++k2) {
        bf16x8 aq = *(const bf16x8*)&Qs[(wave * 16 + lr) * 72 + k2 * 32 + q8 * 8];
#pragma unroll
        for (int j = 0; j < 4; ++j) {
            bf16x8 bk8 = *(const bf16x8*)&Ks[(j * 16 + lr) * 72 + k2 * 32 + q8 * 8];
            sacc[j] = __builtin_amdgcn_mfma_f32_16x16x32_bf16(aq, bk8, sacc[j], 0, 0, 0);
        }
    }
    // --- mask + in-register softmax (rows in C layout)
    const int dst0 = wave * 16 + q8 * 4;
    float p[4][4];
#pragma unroll
    for (int r2 = 0; r2 < 4; ++r2) {
        float m = -1e38f;
#pragma unroll
        for (int j = 0; j < 4; ++j) {
            sacc[j][r2] += Mm[(dst0 + r2) * 64 + j * 16 + lr];
            m = fmaxf(m, sacc[j][r2]);
        }
        m = fmaxf(m, __shfl_xor(m, 1));
        m = fmaxf(m, __shfl_xor(m, 2));
        m = fmaxf(m, __shfl_xor(m, 4));
        m = fmaxf(m, __shfl_xor(m, 8));
        bool dead = (m < -1e29f);
        float rs = 0.f;
#pragma unroll
        for (int j = 0; j < 4; ++j) {
            float pv = dead ? 0.f : __expf(sacc[j][r2] - m);
            p[j][r2] = pv;
            rs += pv;
        }
        rs += __shfl_xor(rs, 1);
        rs += __shfl_xor(rs, 2);
        rs += __shfl_xor(rs, 4);
        rs += __shfl_xor(rs, 8);
        float sc = 1.0f / (rs + 1e-16f) * (1.0f / 64.0f);
#pragma unroll
        for (int j = 0; j < 4; ++j) p[j][r2] *= sc;
    }
    // --- column sums -> w_l
#pragma unroll
    for (int j = 0; j < 4; ++j) {
        float cw = p[j][0] + p[j][1] + p[j][2] + p[j][3];
        cw += __shfl_xor(cw, 16);
        cw += __shfl_xor(cw, 32);
        if (lane < 16) atomicAdd(&w_l[j * 16 + lr], cw);
    }
    __syncthreads();
    // --- y[c] = sum_src w[src] * V[src][c]
    {
        int c = t & 63, sg = t >> 6;
        float part = 0.f;
#pragma unroll
        for (int i = 0; i < 16; ++i) {
            int src = sg * 16 + i;
            part += w_l[src] * bf2f(Vs[src * 72 + c]);
        }
        atomicAdd(&y_l[c], part);
    }
    __syncthreads();
    // --- out[b] += y @ Wr_h
    if (t < 64) {
        float yv = y_l[t];
#pragma unroll
        for (int j = 0; j < 6; ++j) {
            float v = yv * Wr[(h * 64 + t) * 6 + j];
            for (int off = 32; off; off >>= 1) v += __shfl_down(v, off);
            if (t == 0) atomicAdd(&out[b * 6 + j], v);
        }
    }
}

// ---------------------------------------------------------------------------
extern "C" void kernel_launch(void* const* d_in, const int* in_sizes, int n_in,
                              void* d_out, int out_size, void* d_ws, size_t ws_size,
                              hipStream_t stream)
{
    (void)in_sizes; (void)n_in; (void)out_size; (void)ws_size;
    const float* X  = (const float*)d_in[0];
    const int*   ei = (const int*)d_in[1];
    const float* Wp = (const float*)d_in[2];
    const float* bp = (const float*)d_in[3];
    const float* Wq = (const float*)d_in[4];
    const float* bq = (const float*)d_in[5];
    const float* Wk = (const float*)d_in[6];
    const float* bk = (const float*)d_in[7];
    const float* Wv = (const float*)d_in[8];
    const float* bv = (const float*)d_in[9];
    const float* Wsk = (const float*)d_in[10];
    const float* bs = (const float*)d_in[11];
    const float* Wr = (const float*)d_in[12];
    const float* br = (const float*)d_in[13];
    float* out = (float*)d_out;

    char* ws = (char*)d_ws;
    u16*   WpT = (u16*)(ws);                                  // 1 MiB
    u16*   WT  = (u16*)(ws + (1u << 20));                     // 768 KiB
    float* Mm  = (float*)(ws + 0x1C0000u);                    // 16 KiB
    float* Wsr = (float*)(ws + 0x1C4000u);                    // 6 KiB
    float* c0  = (float*)(ws + 0x1C8000u);                    // 24 B
    u16*   Xp  = (u16*)(ws + (2u << 20));                     // 32 MiB

    // weight transposes (tiled, coalesced both sides)
    hipLaunchKernelGGL(transpose_cvt, dim3(4, 32), dim3(256), 0, stream,
                       Wp, WpT, 2048, 256);
    hipLaunchKernelGGL(transpose_cvt, dim3(8, 4), dim3(256), 0, stream,
                       Wq, WT, 256, 512);
    hipLaunchKernelGGL(transpose_cvt, dim3(8, 4), dim3(256), 0, stream,
                       Wk, WT + (size_t)512 * 256, 256, 512);
    hipLaunchKernelGGL(transpose_cvt, dim3(8, 4), dim3(256), 0, stream,
                       Wv, WT + (size_t)1024 * 256, 256, 512);
    hipLaunchKernelGGL(prep_small, dim3(9), dim3(256), 0, stream,
                       ei, Wsk, Wr, bs, bv, br, Mm, Wsr, c0);
    hipLaunchKernelGGL(gemm1, dim3(1024), dim3(256), 0, stream, X, WpT, bp, Xp);
    hipLaunchKernelGGL(skip_out, dim3(1024), dim3(256), 0, stream, Xp, Wsr, c0, out);
    hipLaunchKernelGGL(attn, dim3(8192), dim3(256), 0, stream,
                       Xp, WT, Mm, bq, bk, Wr, out);
}